// Round 4
// baseline (445.190 us; speedup 1.0000x reference)
//
#include <hip/hip_runtime.h>
#include <hip/hip_bf16.h>

#define NEG_SLOPE 0.2f

typedef __attribute__((ext_vector_type(8))) short short8;   // 8 bf16 (4 VGPRs)
typedef __attribute__((ext_vector_type(4))) float f32x4;    // MFMA accumulator
typedef __attribute__((ext_vector_type(2))) unsigned uint2v; // NT-storable 8B

__device__ __forceinline__ float bflo(unsigned u) { return __uint_as_float(u << 16); }
__device__ __forceinline__ float bfhi(unsigned u) { return __uint_as_float(u & 0xffff0000u); }
__device__ __forceinline__ unsigned pk2bf(float a, float b) {
    __hip_bfloat162 t; t.x = __float2bfloat16(a); t.y = __float2bfloat16(b);
    return *reinterpret_cast<unsigned*>(&t);
}

#define KP  136   // padded k-stride for gemm1 tiles (128+8)
#define KP2 264   // padded k-stride for gemm2 tiles (256+8)
#define H1S 288   // h1b row stride in shorts (256 cols + 32 pad -> 576B, spreads L2 sets)
#define H3S 80    // h3b row stride in shorts (64 cols + 16 pad -> 160B, spreads L2 sets)

// ============ init: edge hist + rank (blocks [0,Eb)) + weight prep (rest) ============
__global__ void k_init(const int* __restrict__ ei, int E, int* __restrict__ deg,
    int* __restrict__ rank, const float* __restrict__ W1, const float* __restrict__ W2,
    __hip_bfloat16* __restrict__ W1t, __hip_bfloat16* __restrict__ W2t, int Eb)
{
    int b = blockIdx.x;
    if (b < Eb) {
        int i = b * 256 + threadIdx.x;
        if (i < E) {
            int dst = ei[E + i];
            rank[i] = atomicAdd(&deg[dst], 1);
        }
    } else {
        int i = (b - Eb) * 256 + threadIdx.x;
        if (i < 256 * KP) {
            int n = i / KP, k = i % KP;
            W1t[i] = __float2bfloat16(k < 128 ? W1[k * 256 + n] : 0.f);
        } else {
            int j = i - 256 * KP;
            if (j < 64 * KP2) {
                int n = j / KP2, k = j % KP2;
                W2t[j] = __float2bfloat16(k < 256 ? W2[k * 64 + n] : 0.f);
            }
        }
    }
}

// ============ scan1: per-256-block inclusive scan of (deg+1) -> excl + bsum ============
__global__ __launch_bounds__(256) void k_scan1(const int* __restrict__ deg, int N,
    int* __restrict__ excl, int* __restrict__ bsum)
{
    __shared__ int s[256];
    int t = threadIdx.x, i = blockIdx.x * 256 + t;
    int v = (i < N) ? deg[i] + 1 : 0;
    s[t] = v; __syncthreads();
#pragma unroll
    for (int o = 1; o < 256; o <<= 1) {
        int x = (t >= o) ? s[t - o] : 0;
        __syncthreads();
        s[t] += x;
        __syncthreads();
    }
    if (i < N) excl[i] = s[t] - v;
    if (t == 255) bsum[blockIdx.x] = s[255];
}

// ============ scatter: atomic-free (rank precomputed); self-loop at slot 0 ============
__global__ void k_scatter(const int* __restrict__ ei, const int* __restrict__ rank,
    int E, int N, const int* __restrict__ rowptr, int* __restrict__ csr_src)
{
    int i = blockIdx.x * blockDim.x + threadIdx.x;
    if (i < E) {
        int src = ei[i], dst = ei[E + i];
        csr_src[rowptr[dst] + 1 + rank[i]] = src;
    } else if (i < E + N) {
        int n = i - E;
        csr_src[rowptr[n]] = n;
    }
}

// ============ Layer 1 GEMM via MFMA + fused att dots + piggybacked scan23 ============
__global__ __launch_bounds__(256) void k_gemm1_mfma(
    const float* __restrict__ x, const __hip_bfloat16* __restrict__ W1t,
    const float* __restrict__ as1, const float* __restrict__ ad1,
    __hip_bfloat16* __restrict__ h1b, float* __restrict__ a_s1, float* __restrict__ a_d1,
    int N, int M, const int* __restrict__ excl, const int* __restrict__ bsum,
    int* __restrict__ rowptr, int NB, int G1x)
{
    __shared__ short sA[64 * KP];
    __shared__ short sB[128 * KP];

    if (blockIdx.x >= G1x) {
        int sb = (blockIdx.x - G1x) * 2 + blockIdx.y;
        if (sb >= NB) return;
        int* s = (int*)sA;
        int t = threadIdx.x;
        s[t] = (t < NB) ? bsum[t] : 0;
        __syncthreads();
#pragma unroll
        for (int o = 1; o < 256; o <<= 1) {
            int y = (t >= o) ? s[t - o] : 0;
            __syncthreads();
            s[t] += y;
            __syncthreads();
        }
        int off = (sb == 0) ? 0 : s[sb - 1];
        int i = sb * 256 + t;
        if (i < N) rowptr[i] = excl[i] + off;
        if (i == 0) rowptr[N] = M;
        return;
    }

    const int n0 = blockIdx.x * 64;
    const int c0 = blockIdx.y * 128;
    const int t = threadIdx.x, wv = t >> 6, lane = t & 63;
    const int l15 = lane & 15, q = lane >> 4;

    {
        const float4* x4 = (const float4*)x;
        for (int i = t; i < 2048; i += 256) {
            int row = i >> 5, kq = i & 31;
            float4 v = make_float4(0.f, 0.f, 0.f, 0.f);
            if (n0 + row < N) v = x4[(size_t)(n0 + row) * 32 + kq];
            uint2 p; p.x = pk2bf(v.x, v.y); p.y = pk2bf(v.z, v.w);
            *(uint2*)(sA + row * KP + kq * 4) = p;
        }
    }
    {
        const uint4* src = (const uint4*)((const short*)W1t + (size_t)c0 * KP);
        uint4* dst = (uint4*)sB;
        for (int i = t; i < (128 * KP * 2) / 16; i += 256) dst[i] = src[i];
    }
    __syncthreads();

    short8 af[4];
#pragma unroll
    for (int kc = 0; kc < 4; ++kc)
        af[kc] = *(const short8*)(sA + (wv * 16 + l15) * KP + kc * 32 + q * 8);

    f32x4 acc[8];
#pragma unroll
    for (int nt = 0; nt < 8; ++nt) {
        f32x4 a = {0.f, 0.f, 0.f, 0.f};
#pragma unroll
        for (int kc = 0; kc < 4; ++kc) {
            short8 bf = *(const short8*)(sB + (nt * 16 + l15) * KP + kc * 32 + q * 8);
            a = __builtin_amdgcn_mfma_f32_16x16x32_bf16(af[kc], bf, a, 0, 0, 0);
        }
        acc[nt] = a;
    }

#pragma unroll
    for (int nt = 0; nt < 8; ++nt) {
#pragma unroll
        for (int r = 0; r < 4; ++r) {
            int row = n0 + wv * 16 + q * 4 + r;
            if (row < N)
                h1b[(size_t)row * H1S + c0 + nt * 16 + l15] = __float2bfloat16(acc[nt][r]);
        }
    }

    float asv[8], adv[8];
#pragma unroll
    for (int nt = 0; nt < 8; ++nt) {
        asv[nt] = as1[c0 + nt * 16 + l15];
        adv[nt] = ad1[c0 + nt * 16 + l15];
    }
    const int hb = blockIdx.y * 2;
#pragma unroll
    for (int r = 0; r < 4; ++r) {
        float slo = 0.f, shi = 0.f, dlo = 0.f, dhi = 0.f;
#pragma unroll
        for (int nt = 0; nt < 4; ++nt) { slo += acc[nt][r] * asv[nt]; dlo += acc[nt][r] * adv[nt]; }
#pragma unroll
        for (int nt = 4; nt < 8; ++nt) { shi += acc[nt][r] * asv[nt]; dhi += acc[nt][r] * adv[nt]; }
#pragma unroll
        for (int o = 1; o < 16; o <<= 1) {
            slo += __shfl_xor(slo, o); shi += __shfl_xor(shi, o);
            dlo += __shfl_xor(dlo, o); dhi += __shfl_xor(dhi, o);
        }
        int row = n0 + wv * 16 + q * 4 + r;
        if (l15 == 0 && row < N) {
            a_s1[row * 4 + hb]     = slo; a_s1[row * 4 + hb + 1] = shi;
            a_d1[row * 4 + hb]     = dlo; a_d1[row * 4 + hb + 1] = dhi;
        }
    }
}

// ============ Layer 1 sliced softmax+aggregate+bias+ELU ============
// 8 column-slices (64B each) x dst-groups; slice = blockIdx.x % 8 so each XCD's L2
// holds only its 3.2MB stripe of h1b (row stride 576B spreads L2 sets).
// Per wave: 1 dst at a time; lanes = 8 edge-slots (j=l>>3) x 8 col-chunks (c=l&7, uint2).
// ex/den recomputed per slice from L2-resident a_s1/a_d1 (f32 math identical to before).
__global__ __launch_bounds__(256) void k_agg1s(const int* __restrict__ rowptr,
    const int* __restrict__ csr_src, const float* __restrict__ a_s1,
    const float* __restrict__ a_d1, const __hip_bfloat16* __restrict__ h1b,
    const float* __restrict__ b1, __hip_bfloat16* __restrict__ h2b, int N)
{
    const int tt = threadIdx.x, wv = tt >> 6, l = tt & 63;
    const int s = blockIdx.x & 7;            // slice -> XCD (round-robin dispatch)
    const int dgrp = blockIdx.x >> 3;
    const int j = l >> 3, c = l & 7;
    const int h = s >> 1;                    // head of this 32-col slice
    const char* hb = (const char*)h1b;
    const int sb = s * 64 + c * 8;           // byte offset within padded row
#pragma unroll 1
    for (int i = 0; i < 4; ++i) {
        int dst = dgrp * 16 + wv * 4 + i;
        if (dst >= N) return;
        int st = rowptr[dst], en = rowptr[dst + 1];
        float adh = a_d1[dst * 4 + h];
        float a0 = 0.f, a1 = 0.f, a2 = 0.f, a3 = 0.f, dn = 0.f;
        for (int base = st; base < en; base += 16) {
            int i0 = base + j, i1 = base + 8 + j;
            bool k0 = i0 < en, k1 = i1 < en;
            int c0i = k0 ? i0 : en - 1, c1i = k1 ? i1 : en - 1;
            int s0 = __builtin_nontemporal_load(csr_src + c0i);
            int s1 = __builtin_nontemporal_load(csr_src + c1i);
            float q0 = a_s1[s0 * 4 + h] + adh; q0 = q0 > 0.f ? q0 : NEG_SLOPE * q0;
            float q1 = a_s1[s1 * 4 + h] + adh; q1 = q1 > 0.f ? q1 : NEG_SLOPE * q1;
            float e0 = k0 ? __expf(q0) : 0.f;
            float e1 = k1 ? __expf(q1) : 0.f;
            uint2 g0 = *(const uint2*)(hb + (size_t)s0 * (H1S * 2) + sb);
            uint2 g1 = *(const uint2*)(hb + (size_t)s1 * (H1S * 2) + sb);
            dn += e0 + e1;
            a0 += e0 * bflo(g0.x); a1 += e0 * bfhi(g0.x);
            a2 += e0 * bflo(g0.y); a3 += e0 * bfhi(g0.y);
            a0 += e1 * bflo(g1.x); a1 += e1 * bfhi(g1.x);
            a2 += e1 * bflo(g1.y); a3 += e1 * bfhi(g1.y);
        }
        // reduce across edge-slots (j axis: lane bits 3..5); c fixed -> exact per-col sums
#pragma unroll
        for (int o = 8; o < 64; o <<= 1) {
            a0 += __shfl_xor(a0, o); a1 += __shfl_xor(a1, o);
            a2 += __shfl_xor(a2, o); a3 += __shfl_xor(a3, o);
            dn += __shfl_xor(dn, o);
        }
        if (j == 0) {
            float inv = 1.0f / dn;
            float4 bb = ((const float4*)b1)[s * 8 + c];
            float v0 = a0 * inv + bb.x; v0 = v0 > 0.f ? v0 : (__expf(v0) - 1.f);
            float v1 = a1 * inv + bb.y; v1 = v1 > 0.f ? v1 : (__expf(v1) - 1.f);
            float v2 = a2 * inv + bb.z; v2 = v2 > 0.f ? v2 : (__expf(v2) - 1.f);
            float v3 = a3 * inv + bb.w; v3 = v3 > 0.f ? v3 : (__expf(v3) - 1.f);
            uint2v p; p.x = pk2bf(v0, v1); p.y = pk2bf(v2, v3);
            __builtin_nontemporal_store(p, (uint2v*)((char*)h2b + (size_t)dst * 512 + sb));
        }
    }
}

// ============ Layer 2 GEMM via MFMA + fused att dots (direct stores) ============
__global__ __launch_bounds__(256) void k_gemm2_mfma(
    const __hip_bfloat16* __restrict__ h2b, const __hip_bfloat16* __restrict__ W2t,
    const float* __restrict__ as2, const float* __restrict__ ad2,
    __hip_bfloat16* __restrict__ h3b, float* __restrict__ a_s2, float* __restrict__ a_d2,
    int N)
{
    const int n0 = blockIdx.x * 32;
    const int t = threadIdx.x, wv = t >> 6, lane = t & 63;
    const int l15 = lane & 15, q = lane >> 4;
    const int rs = wv & 1, ch = wv >> 1;

    __shared__ short sA[32 * KP2];
    __shared__ short sB[64 * KP2];

    {
        const uint4* src = (const uint4*)W2t;
        uint4* dst = (uint4*)sB;
        for (int i = t; i < (64 * KP2 * 2) / 16; i += 256) dst[i] = src[i];
    }
    {
        for (int i = t; i < 1024; i += 256) {
            int row = i >> 5, kq = i & 31;
            uint4 v = make_uint4(0, 0, 0, 0);
            if (n0 + row < N) v = ((const uint4*)(h2b + (size_t)(n0 + row) * 256))[kq];
            *(uint4*)(sA + row * KP2 + kq * 8) = v;
        }
    }
    __syncthreads();

    short8 af[8];
#pragma unroll
    for (int kc = 0; kc < 8; ++kc)
        af[kc] = *(const short8*)(sA + (rs * 16 + l15) * KP2 + kc * 32 + q * 8);

    f32x4 acc[2];
#pragma unroll
    for (int nt = 0; nt < 2; ++nt) {
        f32x4 a = {0.f, 0.f, 0.f, 0.f};
#pragma unroll
        for (int kc = 0; kc < 8; ++kc) {
            short8 bf = *(const short8*)(sB + (ch * 32 + nt * 16 + l15) * KP2 + kc * 32 + q * 8);
            a = __builtin_amdgcn_mfma_f32_16x16x32_bf16(af[kc], bf, a, 0, 0, 0);
        }
        acc[nt] = a;
    }

    float asv[2], adv[2];
#pragma unroll
    for (int nt = 0; nt < 2; ++nt) {
        int col = ch * 32 + nt * 16 + l15;
        asv[nt] = as2[col]; adv[nt] = ad2[col];
    }
#pragma unroll
    for (int r = 0; r < 4; ++r) {
        int row = n0 + rs * 16 + q * 4 + r;
        if (row < N) {
#pragma unroll
            for (int nt = 0; nt < 2; ++nt)
                h3b[(size_t)row * H3S + ch * 32 + nt * 16 + l15] = __float2bfloat16(acc[nt][r]);
        }
        float s = acc[0][r] * asv[0] + acc[1][r] * asv[1];
        float d = acc[0][r] * adv[0] + acc[1][r] * adv[1];
#pragma unroll
        for (int o = 1; o < 16; o <<= 1) { s += __shfl_xor(s, o); d += __shfl_xor(d, o); }
        if (l15 == 0 && row < N) {
            atomicAdd(&a_s2[row], s);
            atomicAdd(&a_d2[row], d);
        }
    }
}

// ============ Layer 2 sliced softmax+aggregate + b2 -> out ============
// 2 column-slices (64B each); slice = blockIdx.x & 1 -> even/odd XCDs each hold a
// 3.2MB h3b stripe (row stride 160B). Same lane geometry as k_agg1s.
__global__ __launch_bounds__(256) void k_agg2s(const int* __restrict__ rowptr,
    const int* __restrict__ csr_src, const float* __restrict__ a_s2,
    const float* __restrict__ a_d2, const __hip_bfloat16* __restrict__ h3b,
    const float* __restrict__ b2, float* __restrict__ out, int N)
{
    const int tt = threadIdx.x, wv = tt >> 6, l = tt & 63;
    const int s = blockIdx.x & 1;
    const int dgrp = blockIdx.x >> 1;
    const int j = l >> 3, c = l & 7;
    const char* hb = (const char*)h3b;
    const int sb = s * 64 + c * 8;
#pragma unroll 1
    for (int i = 0; i < 4; ++i) {
        int dst = dgrp * 16 + wv * 4 + i;
        if (dst >= N) return;
        int st = rowptr[dst], en = rowptr[dst + 1];
        float adv = a_d2[dst];
        float a0 = 0.f, a1 = 0.f, a2 = 0.f, a3 = 0.f, dn = 0.f;
        for (int base = st; base < en; base += 16) {
            int i0 = base + j, i1 = base + 8 + j;
            bool k0 = i0 < en, k1 = i1 < en;
            int c0i = k0 ? i0 : en - 1, c1i = k1 ? i1 : en - 1;
            int s0 = __builtin_nontemporal_load(csr_src + c0i);
            int s1 = __builtin_nontemporal_load(csr_src + c1i);
            float q0 = a_s2[s0] + adv; q0 = q0 > 0.f ? q0 : NEG_SLOPE * q0;
            float q1 = a_s2[s1] + adv; q1 = q1 > 0.f ? q1 : NEG_SLOPE * q1;
            float e0 = k0 ? __expf(q0) : 0.f;
            float e1 = k1 ? __expf(q1) : 0.f;
            uint2 g0 = *(const uint2*)(hb + (size_t)s0 * (H3S * 2) + sb);
            uint2 g1 = *(const uint2*)(hb + (size_t)s1 * (H3S * 2) + sb);
            dn += e0 + e1;
            a0 += e0 * bflo(g0.x); a1 += e0 * bfhi(g0.x);
            a2 += e0 * bflo(g0.y); a3 += e0 * bfhi(g0.y);
            a0 += e1 * bflo(g1.x); a1 += e1 * bfhi(g1.x);
            a2 += e1 * bflo(g1.y); a3 += e1 * bfhi(g1.y);
        }
#pragma unroll
        for (int o = 8; o < 64; o <<= 1) {
            a0 += __shfl_xor(a0, o); a1 += __shfl_xor(a1, o);
            a2 += __shfl_xor(a2, o); a3 += __shfl_xor(a3, o);
            dn += __shfl_xor(dn, o);
        }
        if (j == 0) {
            float inv = 1.0f / dn;
            float4 bb = ((const float4*)b2)[s * 8 + c];
            float4 ov;
            ov.x = a0 * inv + bb.x; ov.y = a1 * inv + bb.y;
            ov.z = a2 * inv + bb.z; ov.w = a3 * inv + bb.w;
            ((float4*)(out + (size_t)dst * 64 + s * 32))[c] = ov;
        }
    }
}

extern "C" void kernel_launch(void* const* d_in, const int* in_sizes, int n_in,
                              void* d_out, int out_size, void* d_ws, size_t ws_size,
                              hipStream_t stream)
{
    const float* x   = (const float*)d_in[0];
    const int*   ei  = (const int*)d_in[1];
    const float* W1  = (const float*)d_in[2];
    const float* as1 = (const float*)d_in[3];
    const float* ad1 = (const float*)d_in[4];
    const float* b1  = (const float*)d_in[5];
    const float* W2  = (const float*)d_in[6];
    const float* as2 = (const float*)d_in[7];
    const float* ad2 = (const float*)d_in[8];
    const float* b2  = (const float*)d_in[9];
    float* out = (float*)d_out;

    const int N = in_sizes[0] / 128;      // 50000
    const int E = in_sizes[1] / 2;        // 800000
    const int M = E + N;                  // edges + self loops
    const int NB = (N + 255) / 256;       // scan blocks (196 <= 256)
    const int Eb = (E + 255) / 256;

    // ---- workspace layout (256B-aligned) ----
    char* w = (char*)d_ws;
    size_t o = 0;
    auto alloc = [&](size_t bytes) { size_t r = o; o = (o + bytes + 255) & ~(size_t)255; return r; };
    __hip_bfloat16* h1b   = (__hip_bfloat16*)(w + alloc((size_t)N * H1S * 2)); // 28.8 MB
    float* a_s1           = (float*)(w + alloc((size_t)N * 4 * 4));
    float* a_d1           = (float*)(w + alloc((size_t)N * 4 * 4));
    __hip_bfloat16* h2b   = (__hip_bfloat16*)(w + alloc((size_t)N * 256 * 2)); // 25.6 MB
    __hip_bfloat16* h3b   = (__hip_bfloat16*)(w + alloc((size_t)N * H3S * 2)); // 8 MB
    // zero-block: a_s2 | a_d2 | deg — one memset covers the span
    size_t z0 = o;
    float* a_s2           = (float*)(w + alloc((size_t)N * 4));
    float* a_d2           = (float*)(w + alloc((size_t)N * 4));
    int* deg              = (int*)(w + alloc((size_t)N * 4));
    size_t z1 = o;
    int* rank             = (int*)(w + alloc((size_t)E * 4));                  // 3.2 MB
    int* rowptr           = (int*)(w + alloc((size_t)(N + 1) * 4));
    int* excl             = (int*)(w + alloc((size_t)N * 4));
    int* bsum             = (int*)(w + alloc((size_t)NB * 4));
    int* csr_src          = (int*)(w + alloc((size_t)M * 4));                  // 3.4 MB
    __hip_bfloat16* W1t   = (__hip_bfloat16*)(w + alloc((size_t)256 * KP * 2));
    __hip_bfloat16* W2t   = (__hip_bfloat16*)(w + alloc((size_t)64 * KP2 * 2));

    // ---- zero + init (edge hist/rank + weight prep fused) ----
    hipMemsetAsync(w + z0, 0, z1 - z0, stream);
    const int Pb = (256 * KP + 64 * KP2 + 255) / 256;
    k_init<<<Eb + Pb, 256, 0, stream>>>(ei, E, deg, rank, W1, W2, W1t, W2t, Eb);

    // ---- scan1 (tiny), then gemm1 (+ piggybacked scan23) ----
    k_scan1<<<NB, 256, 0, stream>>>(deg, N, excl, bsum);
    const int G1x = (N + 63) / 64;
    k_gemm1_mfma<<<dim3(G1x + (NB + 1) / 2, 2), 256, 0, stream>>>(
        x, W1t, as1, ad1, h1b, a_s1, a_d1, N, M, excl, bsum, rowptr, NB, G1x);

    // ---- scatter (atomic-free) ----
    k_scatter<<<(M + 255) / 256, 256, 0, stream>>>(ei, rank, E, N, rowptr, csr_src);

    // ---- layer 1 aggregate: 8 XCD-resident column slices ----
    const int DG = (N + 15) / 16;
    k_agg1s<<<8 * DG, 256, 0, stream>>>(rowptr, csr_src, a_s1, a_d1, h1b, b1, h2b, N);

    // ---- layer 2 ----
    k_gemm2_mfma<<<(N + 31) / 32, 256, 0, stream>>>(h2b, W2t, as2, ad2, h3b, a_s2, a_d2, N);
    k_agg2s<<<2 * DG, 256, 0, stream>>>(rowptr, csr_src, a_s2, a_d2, h3b, b2, out, N);
}

// Round 5
// 270.710 us; speedup vs baseline: 1.6445x; 1.6445x over previous
//
#include <hip/hip_runtime.h>
#include <hip/hip_bf16.h>

#define NEG_SLOPE 0.2f

typedef __attribute__((ext_vector_type(8))) short short8;   // 8 bf16 (4 VGPRs)
typedef __attribute__((ext_vector_type(4))) float f32x4;    // MFMA accumulator

__device__ __forceinline__ float bflo(unsigned u) { return __uint_as_float(u << 16); }
__device__ __forceinline__ float bfhi(unsigned u) { return __uint_as_float(u & 0xffff0000u); }
__device__ __forceinline__ unsigned pk2bf(float a, float b) {
    __hip_bfloat162 t; t.x = __float2bfloat16(a); t.y = __float2bfloat16(b);
    return *reinterpret_cast<unsigned*>(&t);
}

#define KP  136   // padded k-stride for gemm1 tiles (128+8)
#define KP2 264   // padded k-stride for gemm2 tiles (256+8)

// ============ init: edge hist + rank (blocks [0,Eb)) + weight prep (rest) ============
__global__ void k_init(const int* __restrict__ ei, int E, int* __restrict__ deg,
    int* __restrict__ rank, const float* __restrict__ W1, const float* __restrict__ W2,
    __hip_bfloat16* __restrict__ W1t, __hip_bfloat16* __restrict__ W2t, int Eb)
{
    int b = blockIdx.x;
    if (b < Eb) {
        int i = b * 256 + threadIdx.x;
        if (i < E) {
            int dst = ei[E + i];
            rank[i] = atomicAdd(&deg[dst], 1);
        }
    } else {
        int i = (b - Eb) * 256 + threadIdx.x;
        if (i < 256 * KP) {
            int n = i / KP, k = i % KP;
            W1t[i] = __float2bfloat16(k < 128 ? W1[k * 256 + n] : 0.f);
        } else {
            int j = i - 256 * KP;
            if (j < 64 * KP2) {
                int n = j / KP2, k = j % KP2;
                W2t[j] = __float2bfloat16(k < 256 ? W2[k * 64 + n] : 0.f);
            }
        }
    }
}

// ============ scan1: per-256-block inclusive scan of (deg+1) -> excl + bsum ============
__global__ __launch_bounds__(256) void k_scan1(const int* __restrict__ deg, int N,
    int* __restrict__ excl, int* __restrict__ bsum)
{
    __shared__ int s[256];
    int t = threadIdx.x, i = blockIdx.x * 256 + t;
    int v = (i < N) ? deg[i] + 1 : 0;
    s[t] = v; __syncthreads();
#pragma unroll
    for (int o = 1; o < 256; o <<= 1) {
        int x = (t >= o) ? s[t - o] : 0;
        __syncthreads();
        s[t] += x;
        __syncthreads();
    }
    if (i < N) excl[i] = s[t] - v;
    if (t == 255) bsum[blockIdx.x] = s[255];
}

// ============ scatter: atomic-free (rank precomputed); self-loop at slot 0 ============
__global__ void k_scatter(const int* __restrict__ ei, const int* __restrict__ rank,
    int E, int N, const int* __restrict__ rowptr, int* __restrict__ csr_src)
{
    int i = blockIdx.x * blockDim.x + threadIdx.x;
    if (i < E) {
        int src = ei[i], dst = ei[E + i];
        csr_src[rowptr[dst] + 1 + rank[i]] = src;
    } else if (i < E + N) {
        int n = i - E;
        csr_src[rowptr[n]] = n;
    }
}

// ============ Layer 1 GEMM via MFMA + fused att dots + piggybacked scan23 ============
__global__ __launch_bounds__(256) void k_gemm1_mfma(
    const float* __restrict__ x, const __hip_bfloat16* __restrict__ W1t,
    const float* __restrict__ as1, const float* __restrict__ ad1,
    __hip_bfloat16* __restrict__ h1b, float* __restrict__ a_s1, float* __restrict__ a_d1,
    int N, int M, const int* __restrict__ excl, const int* __restrict__ bsum,
    int* __restrict__ rowptr, int NB, int G1x)
{
    __shared__ short sA[64 * KP];
    __shared__ short sB[128 * KP];

    if (blockIdx.x >= G1x) {
        int sb = (blockIdx.x - G1x) * 2 + blockIdx.y;
        if (sb >= NB) return;
        int* s = (int*)sA;
        int t = threadIdx.x;
        s[t] = (t < NB) ? bsum[t] : 0;
        __syncthreads();
#pragma unroll
        for (int o = 1; o < 256; o <<= 1) {
            int y = (t >= o) ? s[t - o] : 0;
            __syncthreads();
            s[t] += y;
            __syncthreads();
        }
        int off = (sb == 0) ? 0 : s[sb - 1];
        int i = sb * 256 + t;
        if (i < N) rowptr[i] = excl[i] + off;
        if (i == 0) rowptr[N] = M;
        return;
    }

    const int n0 = blockIdx.x * 64;
    const int c0 = blockIdx.y * 128;
    const int t = threadIdx.x, wv = t >> 6, lane = t & 63;
    const int l15 = lane & 15, q = lane >> 4;

    {
        const float4* x4 = (const float4*)x;
        for (int i = t; i < 2048; i += 256) {
            int row = i >> 5, kq = i & 31;
            float4 v = make_float4(0.f, 0.f, 0.f, 0.f);
            if (n0 + row < N) v = x4[(size_t)(n0 + row) * 32 + kq];
            uint2 p; p.x = pk2bf(v.x, v.y); p.y = pk2bf(v.z, v.w);
            *(uint2*)(sA + row * KP + kq * 4) = p;
        }
    }
    {
        const uint4* src = (const uint4*)((const short*)W1t + (size_t)c0 * KP);
        uint4* dst = (uint4*)sB;
        for (int i = t; i < (128 * KP * 2) / 16; i += 256) dst[i] = src[i];
    }
    __syncthreads();

    short8 af[4];
#pragma unroll
    for (int kc = 0; kc < 4; ++kc)
        af[kc] = *(const short8*)(sA + (wv * 16 + l15) * KP + kc * 32 + q * 8);

    f32x4 acc[8];
#pragma unroll
    for (int nt = 0; nt < 8; ++nt) {
        f32x4 a = {0.f, 0.f, 0.f, 0.f};
#pragma unroll
        for (int kc = 0; kc < 4; ++kc) {
            short8 bf = *(const short8*)(sB + (nt * 16 + l15) * KP + kc * 32 + q * 8);
            a = __builtin_amdgcn_mfma_f32_16x16x32_bf16(af[kc], bf, a, 0, 0, 0);
        }
        acc[nt] = a;
    }

#pragma unroll
    for (int nt = 0; nt < 8; ++nt) {
#pragma unroll
        for (int r = 0; r < 4; ++r) {
            int row = n0 + wv * 16 + q * 4 + r;
            if (row < N)
                h1b[(size_t)row * 256 + c0 + nt * 16 + l15] = __float2bfloat16(acc[nt][r]);
        }
    }

    float asv[8], adv[8];
#pragma unroll
    for (int nt = 0; nt < 8; ++nt) {
        asv[nt] = as1[c0 + nt * 16 + l15];
        adv[nt] = ad1[c0 + nt * 16 + l15];
    }
    const int hb = blockIdx.y * 2;
#pragma unroll
    for (int r = 0; r < 4; ++r) {
        float slo = 0.f, shi = 0.f, dlo = 0.f, dhi = 0.f;
#pragma unroll
        for (int nt = 0; nt < 4; ++nt) { slo += acc[nt][r] * asv[nt]; dlo += acc[nt][r] * adv[nt]; }
#pragma unroll
        for (int nt = 4; nt < 8; ++nt) { shi += acc[nt][r] * asv[nt]; dhi += acc[nt][r] * adv[nt]; }
#pragma unroll
        for (int o = 1; o < 16; o <<= 1) {
            slo += __shfl_xor(slo, o); shi += __shfl_xor(shi, o);
            dlo += __shfl_xor(dlo, o); dhi += __shfl_xor(dhi, o);
        }
        int row = n0 + wv * 16 + q * 4 + r;
        if (l15 == 0 && row < N) {
            a_s1[row * 4 + hb]     = slo; a_s1[row * 4 + hb + 1] = shi;
            a_d1[row * 4 + hb]     = dlo; a_d1[row * 4 + hb + 1] = dhi;
        }
    }
}

// ============ Layer 1 fused softmax+aggregate+bias+ELU (bf16 gather) ============
// 8 dsts per 256-thread block: 4 waves x two 32-lane groups, one dst per group.
// Lane l covers cols [8l, 8l+8) via ONE uint4 (16B): 32 lanes = full 512B row, so
// each wave-wide load inst moves 1KB = 2 edges (2x fewer load insts than 8B/lane).
// No per-element clamps in the hot loop (group-local bounds); clamped tail batch only.
__global__ __launch_bounds__(256) void k_agg1_fused(const int* __restrict__ rowptr,
    const int* __restrict__ csr_src, const float* __restrict__ a_s1,
    const float* __restrict__ a_d1, const __hip_bfloat16* __restrict__ h1b,
    const float* __restrict__ b1, __hip_bfloat16* __restrict__ h2b, int N)
{
    const int tt = threadIdx.x, wv = tt >> 6, t = tt & 63;
    const int half = t >> 5, l = t & 31;
    const int h = l >> 3;                         // head of cols 8l..8l+7
    const int dst = blockIdx.x * 8 + wv * 2 + half;
    const bool valid = dst < N;
    __shared__ int   s_off[4][2][32];
    __shared__ float s_ex[4][2][32][4];
    const char* hbase = (const char*)h1b;
    int start = 0, end = 0;
    if (valid) { start = rowptr[dst]; end = rowptr[dst + 1]; }
    float4 ad = make_float4(0.f, 0.f, 0.f, 0.f);
    if (valid) ad = ((const float4*)a_d1)[dst];
    float d0 = 0.f, d1 = 0.f, d2 = 0.f, d3 = 0.f;
    float a0 = 0.f, a1 = 0.f, a2 = 0.f, a3 = 0.f;
    float a4 = 0.f, a5 = 0.f, a6 = 0.f, a7 = 0.f;

    for (int base = start; base < end; base += 32) {
        int nloc = end - base; if (nloc > 32) nloc = 32;
        if (l < nloc) {
            int src = csr_src[base + l];
            s_off[wv][half][l] = src << 9;        // byte offset src*512
            float4 as = ((const float4*)a_s1)[src];
            float e0 = as.x + ad.x; e0 = e0 > 0.f ? e0 : NEG_SLOPE * e0;
            float e1 = as.y + ad.y; e1 = e1 > 0.f ? e1 : NEG_SLOPE * e1;
            float e2 = as.z + ad.z; e2 = e2 > 0.f ? e2 : NEG_SLOPE * e2;
            float e3 = as.w + ad.w; e3 = e3 > 0.f ? e3 : NEG_SLOPE * e3;
            float x0 = __expf(e0), x1 = __expf(e1), x2 = __expf(e2), x3 = __expf(e3);
            s_ex[wv][half][l][0] = x0; s_ex[wv][half][l][1] = x1;
            s_ex[wv][half][l][2] = x2; s_ex[wv][half][l][3] = x3;
            d0 += x0; d1 += x1; d2 += x2; d3 += x3;
        }
        int e = 0;
        for (; e + 8 <= nloc; e += 8) {           // full 8-deep batches, no clamps
            uint4 v[8];
#pragma unroll
            for (int q = 0; q < 8; ++q)
                v[q] = *(const uint4*)(hbase + (size_t)(unsigned)s_off[wv][half][e + q] + l * 16);
#pragma unroll
            for (int q = 0; q < 8; ++q) {
                float ex = s_ex[wv][half][e + q][h];
                a0 += ex * bflo(v[q].x); a1 += ex * bfhi(v[q].x);
                a2 += ex * bflo(v[q].y); a3 += ex * bfhi(v[q].y);
                a4 += ex * bflo(v[q].z); a5 += ex * bfhi(v[q].z);
                a6 += ex * bflo(v[q].w); a7 += ex * bfhi(v[q].w);
            }
        }
        if (e < nloc) {                           // single clamped tail batch
            uint4 v[8]; float ex8[8];
#pragma unroll
            for (int q = 0; q < 8; ++q) {
                int idx = e + q; bool k = idx < nloc; int cl = k ? idx : 0;
                v[q] = *(const uint4*)(hbase + (size_t)(unsigned)s_off[wv][half][cl] + l * 16);
                ex8[q] = k ? s_ex[wv][half][cl][h] : 0.f;
            }
#pragma unroll
            for (int q = 0; q < 8; ++q) {
                float ex = ex8[q];
                a0 += ex * bflo(v[q].x); a1 += ex * bfhi(v[q].x);
                a2 += ex * bflo(v[q].y); a3 += ex * bfhi(v[q].y);
                a4 += ex * bflo(v[q].z); a5 += ex * bfhi(v[q].z);
                a6 += ex * bflo(v[q].w); a7 += ex * bfhi(v[q].w);
            }
        }
    }
    // denominator reduce within the 32-lane group (offsets <=16 stay in-group)
#pragma unroll
    for (int o = 16; o > 0; o >>= 1) {
        d0 += __shfl_xor(d0, o); d1 += __shfl_xor(d1, o);
        d2 += __shfl_xor(d2, o); d3 += __shfl_xor(d3, o);
    }
    if (!valid) return;
    float den = (h == 0) ? d0 : (h == 1) ? d1 : (h == 2) ? d2 : d3;
    float inv = 1.0f / den;
    float4 bb0 = ((const float4*)b1)[2 * l];
    float4 bb1 = ((const float4*)b1)[2 * l + 1];
    float v0 = a0 * inv + bb0.x; v0 = v0 > 0.f ? v0 : (__expf(v0) - 1.f);
    float v1 = a1 * inv + bb0.y; v1 = v1 > 0.f ? v1 : (__expf(v1) - 1.f);
    float v2 = a2 * inv + bb0.z; v2 = v2 > 0.f ? v2 : (__expf(v2) - 1.f);
    float v3 = a3 * inv + bb0.w; v3 = v3 > 0.f ? v3 : (__expf(v3) - 1.f);
    float v4 = a4 * inv + bb1.x; v4 = v4 > 0.f ? v4 : (__expf(v4) - 1.f);
    float v5 = a5 * inv + bb1.y; v5 = v5 > 0.f ? v5 : (__expf(v5) - 1.f);
    float v6 = a6 * inv + bb1.z; v6 = v6 > 0.f ? v6 : (__expf(v6) - 1.f);
    float v7 = a7 * inv + bb1.w; v7 = v7 > 0.f ? v7 : (__expf(v7) - 1.f);
    uint4 pkt;
    pkt.x = pk2bf(v0, v1); pkt.y = pk2bf(v2, v3);
    pkt.z = pk2bf(v4, v5); pkt.w = pk2bf(v6, v7);
    ((uint4*)h2b)[dst * 32 + l] = pkt;
}

// ============ Layer 2 GEMM via MFMA + fused att dots (direct stores) ============
__global__ __launch_bounds__(256) void k_gemm2_mfma(
    const __hip_bfloat16* __restrict__ h2b, const __hip_bfloat16* __restrict__ W2t,
    const float* __restrict__ as2, const float* __restrict__ ad2,
    __hip_bfloat16* __restrict__ h3b, float* __restrict__ a_s2, float* __restrict__ a_d2,
    int N)
{
    const int n0 = blockIdx.x * 32;
    const int t = threadIdx.x, wv = t >> 6, lane = t & 63;
    const int l15 = lane & 15, q = lane >> 4;
    const int rs = wv & 1, ch = wv >> 1;

    __shared__ short sA[32 * KP2];
    __shared__ short sB[64 * KP2];

    {
        const uint4* src = (const uint4*)W2t;
        uint4* dst = (uint4*)sB;
        for (int i = t; i < (64 * KP2 * 2) / 16; i += 256) dst[i] = src[i];
    }
    {
        for (int i = t; i < 1024; i += 256) {
            int row = i >> 5, kq = i & 31;
            uint4 v = make_uint4(0, 0, 0, 0);
            if (n0 + row < N) v = ((const uint4*)(h2b + (size_t)(n0 + row) * 256))[kq];
            *(uint4*)(sA + row * KP2 + kq * 8) = v;
        }
    }
    __syncthreads();

    short8 af[8];
#pragma unroll
    for (int kc = 0; kc < 8; ++kc)
        af[kc] = *(const short8*)(sA + (rs * 16 + l15) * KP2 + kc * 32 + q * 8);

    f32x4 acc[2];
#pragma unroll
    for (int nt = 0; nt < 2; ++nt) {
        f32x4 a = {0.f, 0.f, 0.f, 0.f};
#pragma unroll
        for (int kc = 0; kc < 8; ++kc) {
            short8 bf = *(const short8*)(sB + (ch * 32 + nt * 16 + l15) * KP2 + kc * 32 + q * 8);
            a = __builtin_amdgcn_mfma_f32_16x16x32_bf16(af[kc], bf, a, 0, 0, 0);
        }
        acc[nt] = a;
    }

    float asv[2], adv[2];
#pragma unroll
    for (int nt = 0; nt < 2; ++nt) {
        int col = ch * 32 + nt * 16 + l15;
        asv[nt] = as2[col]; adv[nt] = ad2[col];
    }
#pragma unroll
    for (int r = 0; r < 4; ++r) {
        int row = n0 + rs * 16 + q * 4 + r;
        if (row < N) {
#pragma unroll
            for (int nt = 0; nt < 2; ++nt)
                h3b[(size_t)row * 64 + ch * 32 + nt * 16 + l15] = __float2bfloat16(acc[nt][r]);
        }
        float s = acc[0][r] * asv[0] + acc[1][r] * asv[1];
        float d = acc[0][r] * adv[0] + acc[1][r] * adv[1];
#pragma unroll
        for (int o = 1; o < 16; o <<= 1) { s += __shfl_xor(s, o); d += __shfl_xor(d, o); }
        if (l15 == 0 && row < N) {
            atomicAdd(&a_s2[row], s);
            atomicAdd(&a_d2[row], d);
        }
    }
}

// ============ Layer 2 fused softmax+aggregate + b2 -> out ============
// 8 dsts/block (4 waves x two 32-lane halves), no barriers, 16-deep ILP.
__global__ __launch_bounds__(256) void k_agg2_fused(const int* __restrict__ rowptr,
    const int* __restrict__ csr_src, const float* __restrict__ a_s2,
    const float* __restrict__ a_d2, const __hip_bfloat16* __restrict__ h3b,
    const float* __restrict__ b2, float* __restrict__ out, int N)
{
    const int tt = threadIdx.x, wv = tt >> 6, t = tt & 63;
    const int half = t >> 5, l = t & 31;
    const int dst = blockIdx.x * 8 + wv * 2 + half;
    const bool valid = dst < N;
    __shared__ int   s_off[4][2][32];
    __shared__ float s_ex[4][2][32];
    int start = 0, end = 0;
    float adv = 0.f;
    if (valid) { start = rowptr[dst]; end = rowptr[dst + 1]; adv = a_d2[dst]; }
    int trips = (end - start + 31) >> 5;
#pragma unroll
    for (int o = 32; o > 0; o >>= 1) { int u = __shfl_xor(trips, o); trips = u > trips ? u : trips; }
    const char* hbase = (const char*)h3b;
    float den = 0.f, acc0 = 0.f, acc1 = 0.f;

    for (int it = 0; it < trips; ++it) {
        int base = start + it * 32;
        int nloc = end - base; if (nloc > 32) nloc = 32; if (nloc < 0) nloc = 0;
        if (l < nloc) {
            int src = csr_src[base + l];
            s_off[wv][half][l] = src << 7;               // byte offset src*128
            float e = a_s2[src] + adv;
            e = e > 0.f ? e : NEG_SLOPE * e;
            float ex = __expf(e);
            s_ex[wv][half][l] = ex;
            den += ex;
        }
        int j = 0;
        for (; j + 15 < nloc; j += 16) {
            unsigned v[16];
#pragma unroll
            for (int q = 0; q < 16; ++q)
                v[q] = *(const unsigned*)(hbase + (size_t)(unsigned)s_off[wv][half][j + q] + l * 4);
#pragma unroll
            for (int q = 0; q < 16; ++q) {
                float e = s_ex[wv][half][j + q];
                acc0 += e * bflo(v[q]); acc1 += e * bfhi(v[q]);
            }
        }
        for (; j + 7 < nloc; j += 8) {
            unsigned v[8];
#pragma unroll
            for (int q = 0; q < 8; ++q)
                v[q] = *(const unsigned*)(hbase + (size_t)(unsigned)s_off[wv][half][j + q] + l * 4);
#pragma unroll
            for (int q = 0; q < 8; ++q) {
                float e = s_ex[wv][half][j + q];
                acc0 += e * bflo(v[q]); acc1 += e * bfhi(v[q]);
            }
        }
        for (; j < nloc; ++j) {
            unsigned v = *(const unsigned*)(hbase + (size_t)(unsigned)s_off[wv][half][j] + l * 4);
            float e = s_ex[wv][half][j];
            acc0 += e * bflo(v); acc1 += e * bfhi(v);
        }
    }
#pragma unroll
    for (int o = 16; o > 0; o >>= 1) den += __shfl_xor(den, o);
    if (valid) {
        float inv = 1.0f / den;
        float2 bb = ((const float2*)b2)[l];
        float2 ov; ov.x = acc0 * inv + bb.x; ov.y = acc1 * inv + bb.y;
        ((float2*)(out + (size_t)dst * 64))[l] = ov;
    }
}

extern "C" void kernel_launch(void* const* d_in, const int* in_sizes, int n_in,
                              void* d_out, int out_size, void* d_ws, size_t ws_size,
                              hipStream_t stream)
{
    const float* x   = (const float*)d_in[0];
    const int*   ei  = (const int*)d_in[1];
    const float* W1  = (const float*)d_in[2];
    const float* as1 = (const float*)d_in[3];
    const float* ad1 = (const float*)d_in[4];
    const float* b1  = (const float*)d_in[5];
    const float* W2  = (const float*)d_in[6];
    const float* as2 = (const float*)d_in[7];
    const float* ad2 = (const float*)d_in[8];
    const float* b2  = (const float*)d_in[9];
    float* out = (float*)d_out;

    const int N = in_sizes[0] / 128;      // 50000
    const int E = in_sizes[1] / 2;        // 800000
    const int M = E + N;                  // edges + self loops
    const int NB = (N + 255) / 256;       // scan blocks (196 <= 256)
    const int Eb = (E + 255) / 256;

    // ---- workspace layout (256B-aligned) ----
    char* w = (char*)d_ws;
    size_t o = 0;
    auto alloc = [&](size_t bytes) { size_t r = o; o = (o + bytes + 255) & ~(size_t)255; return r; };
    __hip_bfloat16* h1b   = (__hip_bfloat16*)(w + alloc((size_t)N * 256 * 2)); // 25.6 MB
    float* a_s1           = (float*)(w + alloc((size_t)N * 4 * 4));
    float* a_d1           = (float*)(w + alloc((size_t)N * 4 * 4));
    __hip_bfloat16* h2b   = (__hip_bfloat16*)(w + alloc((size_t)N * 256 * 2)); // 25.6 MB
    __hip_bfloat16* h3b   = (__hip_bfloat16*)(w + alloc((size_t)N * 64 * 2));  // 6.4 MB
    // zero-block: a_s2 | a_d2 | deg — one memset covers the span
    size_t z0 = o;
    float* a_s2           = (float*)(w + alloc((size_t)N * 4));
    float* a_d2           = (float*)(w + alloc((size_t)N * 4));
    int* deg              = (int*)(w + alloc((size_t)N * 4));
    size_t z1 = o;
    int* rank             = (int*)(w + alloc((size_t)E * 4));                  // 3.2 MB
    int* rowptr           = (int*)(w + alloc((size_t)(N + 1) * 4));
    int* excl             = (int*)(w + alloc((size_t)N * 4));
    int* bsum             = (int*)(w + alloc((size_t)NB * 4));
    int* csr_src          = (int*)(w + alloc((size_t)M * 4));                  // 3.4 MB
    __hip_bfloat16* W1t   = (__hip_bfloat16*)(w + alloc((size_t)256 * KP * 2));
    __hip_bfloat16* W2t   = (__hip_bfloat16*)(w + alloc((size_t)64 * KP2 * 2));

    // ---- zero + init (edge hist/rank + weight prep fused) ----
    hipMemsetAsync(w + z0, 0, z1 - z0, stream);
    const int Pb = (256 * KP + 64 * KP2 + 255) / 256;
    k_init<<<Eb + Pb, 256, 0, stream>>>(ei, E, deg, rank, W1, W2, W1t, W2t, Eb);

    // ---- scan1 (tiny), then gemm1 (+ piggybacked scan23) ----
    k_scan1<<<NB, 256, 0, stream>>>(deg, N, excl, bsum);
    const int G1x = (N + 63) / 64;
    k_gemm1_mfma<<<dim3(G1x + (NB + 1) / 2, 2), 256, 0, stream>>>(
        x, W1t, as1, ad1, h1b, a_s1, a_d1, N, M, excl, bsum, rowptr, NB, G1x);

    // ---- scatter (atomic-free) ----
    k_scatter<<<(M + 255) / 256, 256, 0, stream>>>(ei, rank, E, N, rowptr, csr_src);

    // ---- layer 1 aggregate (8 dsts/block, 32-lane group per dst, uint4 rows) ----
    k_agg1_fused<<<(N + 7) / 8, 256, 0, stream>>>(rowptr, csr_src, a_s1, a_d1, h1b, b1, h2b, N);

    // ---- layer 2 ----
    k_gemm2_mfma<<<(N + 31) / 32, 256, 0, stream>>>(h2b, W2t, as2, ad2, h3b, a_s2, a_d2, N);
    k_agg2_fused<<<(N + 7) / 8, 256, 0, stream>>>(rowptr, csr_src, a_s2, a_d2, h3b, b2, out, N);
}